// Round 4
// baseline (12.456 us; speedup 1.0000x reference)
//
#include <hip/hip_runtime.h>

// CurveEval3: cubic B-spline curve evaluation, faithful to the NumPy
// reference (blowup-sensitive degenerate-knot regions).
// B=4096 curves, M=128 ctrl pts, p=3, OUT_DIM=256 samples, DIM=3. KNOTS=132.
//
// Bitwise-critical pieces (kept exact): u (np.linspace f64 replication),
// span selection (argmin FIRST-index tie-break), dU = (U1-u)+(u-U2) with
// _rn ops + dU==0.0f check. Division via v_rcp_f32 (1-ULP relative, safe
// under the 0.088 absmax threshold; verified absmax 0.0156).
//
// Structure: one block = CPB(4) curves x 256 samples. Each thread owns one
// sample t and loops (fully unrolled) over 4 curves -> 4 independent
// dependent-LDS chains in flight, hiding the ~120cyc ds_read latency that
// dominated the 1-curve/block version.

#define B_N     4096
#define M_N     128
#define P_DEG   3
#define T_N     256
#define KNOTS_N 132
#define CPB     4          // curves per block

__global__ __launch_bounds__(256, 4) void curve_eval_kernel(
    const float* __restrict__ ctrl,   // (B, M, 3)
    const float* __restrict__ knots,  // (B, 132)
    float* __restrict__ out)          // (B, 256, 3)
{
    __shared__ float Uk[CPB][KNOTS_N];     // 4 x 528 B
    __shared__ float cp[CPB][M_N * 4];     // rows padded to 4 -> ds_read_b128

    const int b0 = blockIdx.x * CPB;
    const int t  = threadIdx.x;

    // ---- staging (vectorized, coalesced) ----
    // knots: 4 curves x 33 float4 = 132 float4 loads (bases 16B-aligned)
    if (t < CPB * 33) {
        const int c = t / 33, j = t - c * 33;
        ((float4*)Uk[c])[j] =
            ((const float4*)(knots + (size_t)(b0 + c) * KNOTS_N))[j];
    }
    // ctrl: 4 curves x 96 float4 = 384 loads; scatter into padded LDS rows
    for (int i = t; i < CPB * 96; i += 256) {
        const int c = i / 96, j = i - c * 96;
        float4 v = ((const float4*)(ctrl + (size_t)(b0 + c) * (M_N * 3)))[j];
        const int e = j * 4;
        cp[c][((e + 0) / 3) * 4 + (e + 0) % 3] = v.x;
        cp[c][((e + 1) / 3) * 4 + (e + 1) % 3] = v.y;
        cp[c][((e + 2) / 3) * 4 + (e + 2) % 3] = v.z;
        cp[c][((e + 3) / 3) * 4 + (e + 3) % 3] = v.w;
    }
    __syncthreads();

    // ---- u = np.linspace(1e-5, 1-1e-5, 256) bitwise (f64 then round) ----
    const double start = 1e-5;
    const double stop  = 1.0 - 1e-5;
    const double step  = (stop - start) / 255.0;
    float u;
    if (t == T_N - 1) u = (float)stop;
    else              u = (float)((double)t * step + start);

    // ---- spans: branchless fixed 8-step binary search, 4 curves unrolled
    // cond(i) = fl(u - Uk[3+i]) > 1e-8, monotone (true-prefix); cond(0) is
    // always true (u >= 1e-5). Find LAST true index in [0,128].
    int lo[CPB];
    #pragma unroll
    for (int c = 0; c < CPB; ++c) lo[c] = 0;
    #pragma unroll
    for (int s = 128; s >= 1; s >>= 1) {
        #pragma unroll
        for (int c = 0; c < CPB; ++c) {
            const int cand = lo[c] + s;
            const int idx  = cand <= 128 ? cand : 128;      // safe LDS index
            const float d  = __fsub_rn(u, Uk[c][P_DEG + idx]);
            if (cand <= 128 && d > 1e-8f) lo[c] = cand;
        }
    }
    // np.argmin takes the FIRST index attaining the min: walk back over
    // bitwise-equal-d ties (matters O(1) in degenerate-knot regions).
    #pragma unroll
    for (int c = 0; c < CPB; ++c) {
        const float dmin = __fsub_rn(u, Uk[c][P_DEG + lo[c]]);
        while (lo[c] > 0 && __fsub_rn(u, Uk[c][P_DEG + lo[c] - 1]) == dmin)
            --lo[c];
    }

    // ---- Cox-de Boor + gather + dot, 4 curves unrolled (independent) ----
    #pragma unroll
    for (int c = 0; c < CPB; ++c) {
        const int span = lo[c] + P_DEG;   // in [3,127]

        const float w0 = Uk[c][span - 2];
        const float w1 = Uk[c][span - 1];
        const float w2 = Uk[c][span];
        const float w3 = Uk[c][span + 1];
        const float w4 = Uk[c][span + 2];
        const float w5 = Uk[c][span + 3];

        const float A1 = __fsub_rn(w3, u);
        const float A2 = __fsub_rn(w4, u);
        const float A3 = __fsub_rn(w5, u);
        const float B0 = __fsub_rn(u, w0);
        const float B1 = __fsub_rn(u, w1);
        const float B2 = __fsub_rn(u, w2);

        #define TDIV(N_, a1_, a2_, OUT_)                                \
            {                                                           \
                const float dU = __fadd_rn(a1_, a2_);                   \
                float tmp = __fmul_rn((N_), __builtin_amdgcn_rcpf(dU)); \
                if (dU == 0.0f) tmp = 1e-4f;                            \
                OUT_ = tmp;                                             \
            }

        float t0, t1, t2;
        float N0, N1, N2, N3, saved;
        // k=1
        TDIV(1.0f, A1, B2, t0);
        N0 = __fmul_rn(A1, t0);
        N1 = __fmul_rn(B2, t0);
        // k=2
        TDIV(N0, A1, B1, t0);
        TDIV(N1, A2, B2, t1);
        N0    = __fmul_rn(A1, t0);
        saved = __fmul_rn(B1, t0);
        N1    = __fadd_rn(saved, __fmul_rn(A2, t1));
        N2    = __fmul_rn(B2, t1);
        // k=3
        TDIV(N0, A1, B0, t0);
        TDIV(N1, A2, B1, t1);
        TDIV(N2, A3, B2, t2);
        N0    = __fmul_rn(A1, t0);
        saved = __fmul_rn(B0, t0);
        N1    = __fadd_rn(saved, __fmul_rn(A2, t1));
        saved = __fmul_rn(B1, t1);
        N2    = __fadd_rn(saved, __fmul_rn(A3, t2));
        N3    = __fmul_rn(B2, t2);
        #undef TDIV

        const float4 c0 = *(const float4*)&cp[c][(span - 3) * 4];
        const float4 c1 = *(const float4*)&cp[c][(span - 2) * 4];
        const float4 c2 = *(const float4*)&cp[c][(span - 1) * 4];
        const float4 c3 = *(const float4*)&cp[c][(span - 0) * 4];

        float acc0, acc1, acc2;
        acc0 = __fmul_rn(N0, c0.x);
        acc1 = __fmul_rn(N0, c0.y);
        acc2 = __fmul_rn(N0, c0.z);
        acc0 = __fadd_rn(acc0, __fmul_rn(N1, c1.x));
        acc1 = __fadd_rn(acc1, __fmul_rn(N1, c1.y));
        acc2 = __fadd_rn(acc2, __fmul_rn(N1, c1.z));
        acc0 = __fadd_rn(acc0, __fmul_rn(N2, c2.x));
        acc1 = __fadd_rn(acc1, __fmul_rn(N2, c2.y));
        acc2 = __fadd_rn(acc2, __fmul_rn(N2, c2.z));
        acc0 = __fadd_rn(acc0, __fmul_rn(N3, c3.x));
        acc1 = __fadd_rn(acc1, __fmul_rn(N3, c3.y));
        acc2 = __fadd_rn(acc2, __fmul_rn(N3, c3.z));

        float* o = out + ((size_t)(b0 + c) * T_N + t) * 3;
        o[0] = acc0;
        o[1] = acc1;
        o[2] = acc2;
    }
}

extern "C" void kernel_launch(void* const* d_in, const int* in_sizes, int n_in,
                              void* d_out, int out_size, void* d_ws, size_t ws_size,
                              hipStream_t stream) {
    const float* ctrl  = (const float*)d_in[0];   // (4096, 128, 3) f32
    const float* knots = (const float*)d_in[1];   // (4096, 132)   f32
    float* out = (float*)d_out;                   // (4096, 256, 3) f32

    curve_eval_kernel<<<dim3(B_N / CPB), dim3(T_N), 0, stream>>>(ctrl, knots, out);
}